// Round 10
// baseline (849.298 us; speedup 1.0000x reference)
//
#include <hip/hip_runtime.h>
#include <hip/hip_bf16.h>
#include <math.h>

#define B_  128
#define S_  2048
#define DI  512
#define DC  512

typedef __attribute__((ext_vector_type(8))) __bf16 bf16x8;
typedef __attribute__((ext_vector_type(4))) float  f32x4;
typedef __attribute__((ext_vector_type(8))) unsigned short us8;

__device__ __forceinline__ float fast_tanh(float x) {
    float e = __expf(2.f * x);
    return 1.f - 2.f * __builtin_amdgcn_rcpf(e + 1.f);
}

__device__ __forceinline__ unsigned short f2bf(float f) {
    unsigned int u = __float_as_uint(f);
    u += 0x7FFF + ((u >> 16) & 1);   // RNE
    return (unsigned short)(u >> 16);
}

__device__ __forceinline__ unsigned int pk2(float a, float b) {
    union { __hip_bfloat162 h; unsigned int u; } c;
    c.h = __float22bfloat162_rn(make_float2(a, b));
    return c.u;
}

__device__ __forceinline__ float bf2f(unsigned int lo16) {
    return __uint_as_float(lo16 << 16);
}

// ---- fused prep: qb (blocks 0..511) + WtF repack (blocks 512..639) ----
__global__ __launch_bounds__(256) void prep_kernel(
    const float* __restrict__ input, const float* __restrict__ W_in,
    const float* __restrict__ b_in, const float* __restrict__ b_ctx,
    const float* __restrict__ W_ctx,
    float* __restrict__ qb, unsigned short* __restrict__ WtF)
{
    __shared__ float sIn[DI];
    __shared__ float part[2][128];
    const int bx = blockIdx.x, t = threadIdx.x;
    if (bx < 512) {
        int b = bx >> 2, cg = bx & 3;
        for (int i = t; i < DI; i += 256) sIn[i] = input[b * DI + i];
        __syncthreads();
        int e = cg * 128 + (t & 127);
        int dh = t >> 7;
        float a = 0.f;
        const float* wp = W_in + (size_t)(dh * 256) * DC + e;
        #pragma unroll 4
        for (int d = 0; d < 256; ++d) a += sIn[dh * 256 + d] * wp[(size_t)d * DC];
        part[dh][t & 127] = a;
        __syncthreads();
        if (t < 128) {
            int ee = cg * 128 + t;
            qb[b * DC + ee] = b_in[ee] + b_ctx[ee] + part[0][t] + part[1][t];
        }
    } else {
        // WtF[s][g][lane][j] = bf16(W_ctx[s*32 + (lane>>4)*8 + j][g*16 + (lane&15)])
        int tid = (bx - 512) * 256 + t;       // [0, 16*32*64)
        int s   = tid >> 11;
        int rem = tid & 2047;
        int g   = rem >> 6;
        int l   = rem & 63;
        int c   = g * 16 + (l & 15);
        int k0  = s * 32 + (l >> 4) * 8;
        us8 wv;
        #pragma unroll
        for (int j = 0; j < 8; ++j)
            wv[j] = f2bf(W_ctx[(size_t)(k0 + j) * DC + c]);
        *(us8*)(WtF + (size_t)tid * 8) = wv;
    }
}

// ---- score kernel helpers (512 threads) ----
// staging quantum: 8 rows x 512 cols fp32; one wave stages one 2KB row.
struct StQ { float4 a, b; };

__device__ __forceinline__ void loadQ(StQ& q, const float* __restrict__ ctx,
                                      int rowbase, int t) {
    const float* p = ctx + (size_t)(rowbase + (t >> 6)) * DC + (t & 63) * 8;
    q.a = ((const float4*)p)[0];
    q.b = ((const float4*)p)[1];
}

__device__ __forceinline__ void writeQ(const StQ& q, unsigned short* buf,
                                       int qrow, int t) {
    int r = qrow + (t >> 6);
    int cb = (t & 63) * 16;
    uint4 p4 = {pk2(q.a.x, q.a.y), pk2(q.a.z, q.a.w),
                pk2(q.b.x, q.b.y), pk2(q.b.z, q.b.w)};
    *(uint4*)((char*)buf + ((r * 1024 + cb) ^ ((r & 7) << 4))) = p4;
}

__device__ __forceinline__ void ldB2(bf16x8& b0, bf16x8& b1,
                                     const unsigned short* __restrict__ WtF,
                                     int p, int s, int w, int lane) {
    const us8* ws = (const us8*)(WtF + (((size_t)s * 32 + p * 16 + w * 2) * 64 + lane) * 8);
    b0 = *(const bf16x8*)(ws);
    b1 = *(const bf16x8*)(ws + 64);
}

__device__ __forceinline__ void ldA(bf16x8 (&af)[4], const unsigned short* buf,
                                    int s, int lr, int half) {
    #pragma unroll
    for (int fm = 0; fm < 4; ++fm) {
        int r = fm * 16 + lr;
        af[fm] = *(const bf16x8*)((const char*)buf +
                    ((r * 1024 + s * 64 + half * 16) ^ ((r & 7) << 4)));
    }
}

#define RBAR() do { \
    asm volatile("s_waitcnt lgkmcnt(0)" ::: "memory"); \
    __builtin_amdgcn_s_barrier(); \
    __builtin_amdgcn_sched_barrier(0); \
} while (0)

// One 16-K-step pass over 256 cols, with staging slots at s=0,4,8,12.
#define PASS(p) do { \
    bf16x8 be0, be1, bo0, bo1; \
    ldB2(be0, be1, WtF, p, 0, w, lane); \
    _Pragma("unroll") \
    for (int s2 = 0; s2 < 8; ++s2) { \
        const int se = 2 * s2, so = se + 1; \
        if ((s2 & 1) == 0) { \
            const int slot = (p) * 4 + (s2 >> 1); \
            const int tgt = slot + 2; \
            if (stg) { \
                if ((slot & 1) == 0) writeQ(Qa, bufn, slot * 8, t); \
                else                 writeQ(Qb, bufn, slot * 8, t); \
            } \
            if (tgt < 8) { \
                if (stg) { \
                    if ((tgt & 1) == 0) loadQ(Qa, ctx, nr0 + tgt * 8, t); \
                    else                loadQ(Qb, ctx, nr0 + tgt * 8, t); \
                } \
            } else if (st2) { \
                if ((tgt & 1) == 0) loadQ(Qa, ctx, n2r0 + (tgt - 8) * 8, t); \
                else                loadQ(Qb, ctx, n2r0 + (tgt - 8) * 8, t); \
            } \
        } \
        ldB2(bo0, bo1, WtF, p, so, w, lane); \
        bf16x8 af[4]; \
        ldA(af, bufc, se, lr, half); \
        __builtin_amdgcn_s_setprio(1); \
        _Pragma("unroll") \
        for (int fm = 0; fm < 4; ++fm) { \
            acc[fm][0] = __builtin_amdgcn_mfma_f32_16x16x32_bf16(af[fm], be0, acc[fm][0], 0, 0, 0); \
            acc[fm][1] = __builtin_amdgcn_mfma_f32_16x16x32_bf16(af[fm], be1, acc[fm][1], 0, 0, 0); \
        } \
        __builtin_amdgcn_s_setprio(0); \
        if (s2 < 7) ldB2(be0, be1, WtF, p, se + 2, w, lane); \
        ldA(af, bufc, so, lr, half); \
        __builtin_amdgcn_s_setprio(1); \
        _Pragma("unroll") \
        for (int fm = 0; fm < 4; ++fm) { \
            acc[fm][0] = __builtin_amdgcn_mfma_f32_16x16x32_bf16(af[fm], bo0, acc[fm][0], 0, 0, 0); \
            acc[fm][1] = __builtin_amdgcn_mfma_f32_16x16x32_bf16(af[fm], bo1, acc[fm][1], 0, 0, 0); \
        } \
        __builtin_amdgcn_s_setprio(0); \
    } \
} while (0)

#define FOLD(p) do { \
    _Pragma("unroll") \
    for (int fm = 0; fm < 4; ++fm) \
        _Pragma("unroll") \
        for (int reg = 0; reg < 4; ++reg) \
            srow[fm][reg] += wv[p][0] * fast_tanh(qv[p][0] + acc[fm][0][reg]) \
                           + wv[p][1] * fast_tanh(qv[p][1] + acc[fm][1][reg]); \
} while (0)

// Persistent fused score kernel: 256 blocks (1/CU) x 512 threads (8 waves).
// 16 contiguous 64-row tiles; double-buffered bf16 LDS tiles; per tile TWO
// col-passes (256 cols each) so acc[4][2]=32 VGPR; total working set ~120 regs.
__global__ __launch_bounds__(512) void score_kernel(
    const float* __restrict__ ctx,          // [B*S, DC] fp32
    const unsigned short* __restrict__ WtF, // fragment-ordered bf16
    const float* __restrict__ qb,           // [B][DC]
    const float* __restrict__ wsc,          // [DC]
    const int* __restrict__ mask,           // [B*S]
    float* __restrict__ scores_ws,          // [B*S]
    float* __restrict__ pv_ws,              // [ntiles][512]
    float* __restrict__ ml_ws)              // [ntiles][2]
{
    __shared__ __align__(16) unsigned short ctxs[2][64 * 512]; // 2 x 64 KB
    __shared__ float sred[8][64];
    __shared__ float sp[64];

    const int t = threadIdx.x;
    const int bx = blockIdx.x;
    const int lane = t & 63;
    const int w = t >> 6;                   // wave 0..7
    const int lr = lane & 15, half = lane >> 4;
    const int bidx = bx >> 1;               // block-constant batch index

    float wv[2][2], qv[2][2];
    #pragma unroll
    for (int p = 0; p < 2; ++p)
        #pragma unroll
        for (int fn = 0; fn < 2; ++fn) {
            int j = p * 256 + w * 32 + fn * 16 + lr;
            wv[p][fn] = wsc[j];
            qv[p][fn] = qb[bidx * DC + j];
        }

    StQ Qa, Qb;
    const int t0r = bx * 1024;              // first row of this block
    // ---- prologue: stage tile 0 (8 quanta), then preload tile1 q0,q1 ----
    loadQ(Qa, ctx, t0r, t);
    loadQ(Qb, ctx, t0r + 8, t);
    writeQ(Qa, ctxs[0], 0, t);  loadQ(Qa, ctx, t0r + 16, t);
    writeQ(Qb, ctxs[0], 8, t);  loadQ(Qb, ctx, t0r + 24, t);
    writeQ(Qa, ctxs[0], 16, t); loadQ(Qa, ctx, t0r + 32, t);
    writeQ(Qb, ctxs[0], 24, t); loadQ(Qb, ctx, t0r + 40, t);
    writeQ(Qa, ctxs[0], 32, t); loadQ(Qa, ctx, t0r + 48, t);
    writeQ(Qb, ctxs[0], 40, t); loadQ(Qb, ctx, t0r + 56, t);
    writeQ(Qa, ctxs[0], 48, t); loadQ(Qa, ctx, t0r + 64, t);      // tile1 q0
    writeQ(Qb, ctxs[0], 56, t); loadQ(Qb, ctx, t0r + 72, t);      // tile1 q1
    RBAR();

    int cur = 0;
    #pragma unroll 1
    for (int it = 0; it < 16; ++it) {
        const int tile = bx * 16 + it;
        const int row0 = tile * 64;
        const int nr0 = row0 + 64;
        const int n2r0 = row0 + 128;
        const bool stg = it < 15, st2 = it < 14;
        unsigned short* bufc = ctxs[cur];
        unsigned short* bufn = ctxs[cur ^ 1];

        float srow[4][4] = {};
        f32x4 acc[4][2];

        #pragma unroll
        for (int fm = 0; fm < 4; ++fm) { acc[fm][0] = (f32x4){0,0,0,0}; acc[fm][1] = (f32x4){0,0,0,0}; }
        PASS(0);
        FOLD(0);
        #pragma unroll
        for (int fm = 0; fm < 4; ++fm) { acc[fm][0] = (f32x4){0,0,0,0}; acc[fm][1] = (f32x4){0,0,0,0}; }
        PASS(1);
        FOLD(1);

        // ---- reduce row-sums over the 16 col-lanes ----
        #pragma unroll
        for (int fm = 0; fm < 4; ++fm) {
            #pragma unroll
            for (int reg = 0; reg < 4; ++reg) {
                float ssum = srow[fm][reg];
                #pragma unroll
                for (int m = 8; m >= 1; m >>= 1)
                    ssum += __shfl_xor(ssum, m, 64);
                if (lr == 0)
                    sred[w][fm * 16 + half * 4 + reg] = ssum;
            }
        }
        RBAR();

        if (t < 64) {                        // wave 0: block softmax partials
            float sc = sred[0][t] + sred[1][t] + sred[2][t] + sred[3][t]
                     + sred[4][t] + sred[5][t] + sred[6][t] + sred[7][t];
            if (mask[row0 + t] != 0) sc = -1e30f;
            scores_ws[row0 + t] = sc;
            float mx = sc;
            #pragma unroll
            for (int m = 32; m >= 1; m >>= 1) mx = fmaxf(mx, __shfl_xor(mx, m, 64));
            float pe = __expf(sc - mx);
            sp[t] = pe;
            float ls = pe;
            #pragma unroll
            for (int m = 32; m >= 1; m >>= 1) ls += __shfl_xor(ls, m, 64);
            if (t == 0) {
                ml_ws[tile * 2]     = mx;
                ml_ws[tile * 2 + 1] = ls;
            }
        }
        RBAR();

        // ---- pv partial: thread t = col t, 64 rows from LDS ----
        {
            float a0 = 0.f;
            #pragma unroll 8
            for (int s2 = 0; s2 < 64; ++s2) {
                unsigned int u = *(const unsigned short*)
                    ((const char*)bufc + ((s2 * 1024 + t * 2) ^ ((s2 & 7) << 4)));
                a0 += sp[s2] * bf2f(u);
            }
            pv_ws[(size_t)tile * 512 + t] = a0;
        }
        RBAR();

        cur ^= 1;
    }
}

// ---- fused tail: exact softmax merge + attn + ctxv + output GEMM ----
__global__ __launch_bounds__(256) void tail_kernel(
    const float* __restrict__ pv, const float* __restrict__ ml,
    const float* __restrict__ scores, const float* __restrict__ input,
    const float* __restrict__ W_out, const float* __restrict__ b_out,
    float* __restrict__ x, float* __restrict__ attn)
{
    int b = blockIdx.x, hf = blockIdx.y, t = threadIdx.x;
    __shared__ float sw[32];
    __shared__ float scm[1024];
    __shared__ float mlds[2];
    if (t < 32) {
        float m = ml[(b * 32 + t) * 2];
        float l = ml[(b * 32 + t) * 2 + 1];
        float mx = m;
        #pragma unroll
        for (int mm = 16; mm >= 1; mm >>= 1) mx = fmaxf(mx, __shfl_xor(mx, mm, 64));
        float wgt = __expf(m - mx);
        sw[t] = wgt;
        float ls = wgt * l;
        #pragma unroll
        for (int mm = 16; mm >= 1; mm >>= 1) ls += __shfl_xor(ls, mm, 64);
        if (t == 0) { mlds[0] = mx; mlds[1] = 1.f / ls; }
    }
    __syncthreads();
    const float mstar = mlds[0], invL = mlds[1];

    {   // ctxv -> scm[0..511]
        int d0 = t * 2;
        float c0 = 0.f, c1 = 0.f;
        #pragma unroll 4
        for (int j = 0; j < 32; ++j) {
            float wgt = sw[j];
            const float2 v = *(const float2*)(pv + (size_t)(b * 32 + j) * 512 + d0);
            c0 += wgt * v.x; c1 += wgt * v.y;
        }
        scm[d0] = c0 * invL; scm[d0 + 1] = c1 * invL;
    }
    for (int i = t; i < DI; i += 256) scm[512 + i] = input[b * DI + i];
    if (hf == 0) {
        #pragma unroll
        for (int k = 0; k < 8; ++k) {
            int s = k * 256 + t;
            attn[(size_t)b * S_ + s] = __expf(scores[(size_t)b * S_ + s] - mstar) * invL;
        }
    }
    __syncthreads();

    int e = hf * 256 + t;
    float a = b_out[e];
    #pragma unroll 4
    for (int d = 0; d < 1024; ++d) a += scm[d] * W_out[(size_t)d * DI + e];
    x[b * DI + e] = fast_tanh(a);
}

extern "C" void kernel_launch(void* const* d_in, const int* in_sizes, int n_in,
                              void* d_out, int out_size, void* d_ws, size_t ws_size,
                              hipStream_t stream) {
    const float* input = (const float*)d_in[0];
    const float* ctx   = (const float*)d_in[1];
    const int*   mask  = (const int*)d_in[2];
    const float* W_in  = (const float*)d_in[3];
    const float* b_in  = (const float*)d_in[4];
    const float* W_ctx = (const float*)d_in[5];
    const float* b_ctx = (const float*)d_in[6];
    const float* wsc   = (const float*)d_in[7];
    const float* W_out = (const float*)d_in[8];
    const float* b_out = (const float*)d_in[9];

    float* x_out = (float*)d_out;               // [B, DI]
    float* attn  = (float*)d_out + B_ * DI;     // [B, S]

    const int NTILE = (B_ * S_) / 64;           // 4096 tiles of 64 rows

    char* ws = (char*)d_ws;
    float* qb = (float*)ws;                    ws += (size_t)B_ * DC * 4;
    unsigned short* WtF = (unsigned short*)ws; ws += (size_t)DC * DC * 2;
    float* scores_ws = (float*)ws;             ws += (size_t)B_ * S_ * 4;
    float* pv_ws = (float*)ws;                 ws += (size_t)NTILE * 512 * 4;
    float* ml_ws = (float*)ws;                 ws += (size_t)NTILE * 2 * 4;

    prep_kernel<<<640, 256, 0, stream>>>(input, W_in, b_in, b_ctx, W_ctx, qb, WtF);
    score_kernel<<<256, 512, 0, stream>>>(ctx, WtF, qb, wsc, mask,
                                          scores_ws, pv_ws, ml_ws);
    tail_kernel<<<dim3(B_, 2), 256, 0, stream>>>(pv_ws, ml_ws, scores_ws, input,
                                                 W_out, b_out, x_out, attn);
}

// Round 11
// 345.964 us; speedup vs baseline: 2.4549x; 2.4549x over previous
//
#include <hip/hip_runtime.h>
#include <hip/hip_bf16.h>
#include <math.h>

#define B_  128
#define S_  2048
#define DI  512
#define DC  512

typedef __attribute__((ext_vector_type(8))) __bf16 bf16x8;
typedef __attribute__((ext_vector_type(4))) float  f32x4;
typedef __attribute__((ext_vector_type(8))) unsigned short us8;
typedef __attribute__((ext_vector_type(4))) unsigned short us4;

__device__ __forceinline__ float fast_tanh(float x) {
    float e = __expf(2.f * x);
    return 1.f - 2.f * __builtin_amdgcn_rcpf(e + 1.f);
}

__device__ __forceinline__ unsigned short f2bf(float f) {
    unsigned int u = __float_as_uint(f);
    u += 0x7FFF + ((u >> 16) & 1);   // RNE
    return (unsigned short)(u >> 16);
}

__device__ __forceinline__ unsigned int pk2(float a, float b) {
    union { __hip_bfloat162 h; unsigned int u; } c;
    c.h = __float22bfloat162_rn(make_float2(a, b));
    return c.u;
}

__device__ __forceinline__ float bf2f(unsigned int lo16) {
    return __uint_as_float(lo16 << 16);
}

// ---- fused prep: qb (blocks 0..511) + WtF repack (blocks 512..639) ----
__global__ __launch_bounds__(256) void prep_kernel(
    const float* __restrict__ input, const float* __restrict__ W_in,
    const float* __restrict__ b_in, const float* __restrict__ b_ctx,
    const float* __restrict__ W_ctx,
    float* __restrict__ qb, unsigned short* __restrict__ WtF)
{
    __shared__ float sIn[DI];
    __shared__ float part[2][128];
    const int bx = blockIdx.x, t = threadIdx.x;
    if (bx < 512) {
        int b = bx >> 2, cg = bx & 3;
        for (int i = t; i < DI; i += 256) sIn[i] = input[b * DI + i];
        __syncthreads();
        int e = cg * 128 + (t & 127);
        int dh = t >> 7;
        float a = 0.f;
        const float* wp = W_in + (size_t)(dh * 256) * DC + e;
        #pragma unroll 4
        for (int d = 0; d < 256; ++d) a += sIn[dh * 256 + d] * wp[(size_t)d * DC];
        part[dh][t & 127] = a;
        __syncthreads();
        if (t < 128) {
            int ee = cg * 128 + t;
            qb[b * DC + ee] = b_in[ee] + b_ctx[ee] + part[0][t] + part[1][t];
        }
    } else {
        // WtF[s][g][lane][j] = bf16(W_ctx[s*32 + (lane>>4)*8 + j][g*16 + (lane&15)])
        int tid = (bx - 512) * 256 + t;       // [0, 16*32*64)
        int s   = tid >> 11;
        int rem = tid & 2047;
        int g   = rem >> 6;
        int l   = rem & 63;
        int c   = g * 16 + (l & 15);
        int k0  = s * 32 + (l >> 4) * 8;
        us8 wv;
        #pragma unroll
        for (int j = 0; j < 8; ++j)
            wv[j] = f2bf(W_ctx[(size_t)(k0 + j) * DC + c]);
        *(us8*)(WtF + (size_t)tid * 8) = wv;
    }
}

// Fused score kernel: ROUND-4 champion structure, verbatim.
// 4096 blocks x 512 threads (8 waves), 2 blocks/CU, one 64-row tile each.
// Wave w owns cols [w*64, +64) x all 64 rows: acc[4][4]. Barrier-free K-loop.
__global__ __launch_bounds__(512) void score_kernel(
    const float* __restrict__ ctx,          // [B*S, DC] fp32
    const unsigned short* __restrict__ WtF, // fragment-ordered bf16
    const float* __restrict__ qb,           // [B][DC]
    const float* __restrict__ wsc,          // [DC]
    const int* __restrict__ mask,           // [B*S]
    float* __restrict__ scores_ws,          // [B*S]
    float* __restrict__ pv_ws,              // [ntiles][512]
    float* __restrict__ ml_ws)              // [ntiles][2]
{
    __shared__ __align__(16) unsigned short ctxs[64 * 512];  // 64 KB swizzled
    __shared__ float sred[8][64];
    __shared__ float sp[64];
    __shared__ float pvpart[4][512];                         // 8 KB

    const int t = threadIdx.x;
    const int row0 = blockIdx.x * 64;
    const int bidx = row0 >> 11;
    const int lane = t & 63;
    const int w = t >> 6;                   // wave 0..7 = col slice
    const int lr = lane & 15, half = lane >> 4;

    // ---- stage ctx -> bf16 LDS (only HBM read of ctx) ----
    #pragma unroll
    for (int i = 0; i < 8; ++i) {
        int u = i * 512 + t;
        int r = u >> 6, kg = u & 63;
        const float4* src = (const float4*)(ctx + (size_t)(row0 + r) * DC + kg * 8);
        float4 va = src[0], vb = src[1];
        unsigned int p0 = pk2(va.x, va.y), p1 = pk2(va.z, va.w);
        unsigned int p2 = pk2(vb.x, vb.y), p3 = pk2(vb.z, vb.w);
        uint4 pk = {p0, p1, p2, p3};
        *(uint4*)((char*)ctxs + ((r * 1024 + kg * 16) ^ ((r & 7) << 4))) = pk;
    }
    __syncthreads();

    // ---- K-loop: free-running, no barriers ----
    f32x4 acc[4][4] = {};
    #pragma unroll 2
    for (int s = 0; s < 16; ++s) {
        bf16x8 bfr[4];
        const us8* wsrc = (const us8*)(WtF +
            (((size_t)s * 32 + w * 4) * 64 + lane) * 8);
        #pragma unroll
        for (int fn = 0; fn < 4; ++fn)
            bfr[fn] = *(const bf16x8*)(wsrc + fn * 64);
        bf16x8 af[4];
        #pragma unroll
        for (int fm = 0; fm < 4; ++fm) {
            int r = fm * 16 + lr;
            af[fm] = *(const bf16x8*)((const char*)ctxs +
                        ((r * 1024 + s * 64 + half * 16) ^ ((r & 7) << 4)));
        }
        __builtin_amdgcn_s_setprio(1);
        #pragma unroll
        for (int fm = 0; fm < 4; ++fm)
            #pragma unroll
            for (int fn = 0; fn < 4; ++fn)
                acc[fm][fn] = __builtin_amdgcn_mfma_f32_16x16x32_bf16(
                    af[fm], bfr[fn], acc[fm][fn], 0, 0, 0);
        __builtin_amdgcn_s_setprio(0);
    }

    // ---- epilogue: fold tanh, reduce rows ----
    float wv[4], qv[4];
    #pragma unroll
    for (int fn = 0; fn < 4; ++fn) {
        int j = w * 64 + fn * 16 + lr;
        wv[fn] = wsc[j];
        qv[fn] = qb[bidx * DC + j];
    }
    #pragma unroll
    for (int fm = 0; fm < 4; ++fm) {
        #pragma unroll
        for (int reg = 0; reg < 4; ++reg) {
            float ssum = 0.f;
            #pragma unroll
            for (int fn = 0; fn < 4; ++fn)
                ssum += wv[fn] * fast_tanh(qv[fn] + acc[fm][fn][reg]);
            #pragma unroll
            for (int m = 8; m >= 1; m >>= 1)
                ssum += __shfl_xor(ssum, m, 64);
            if (lr == 0)
                sred[w][fm * 16 + half * 4 + reg] = ssum;
        }
    }
    __syncthreads();

    if (t < 64) {                        // wave 0: block softmax partials
        float sc = sred[0][t] + sred[1][t] + sred[2][t] + sred[3][t]
                 + sred[4][t] + sred[5][t] + sred[6][t] + sred[7][t];
        if (mask[row0 + t] != 0) sc = -1e30f;
        scores_ws[row0 + t] = sc;
        float mx = sc;
        #pragma unroll
        for (int m = 32; m >= 1; m >>= 1) mx = fmaxf(mx, __shfl_xor(mx, m, 64));
        float pe = __expf(sc - mx);
        sp[t] = pe;
        float ls = pe;
        #pragma unroll
        for (int m = 32; m >= 1; m >>= 1) ls += __shfl_xor(ls, m, 64);
        if (t == 0) {
            ml_ws[blockIdx.x * 2]     = mx;
            ml_ws[blockIdx.x * 2 + 1] = ls;
        }
    }
    __syncthreads();

    // ---- pv partial: vectorized (4 cols x 16 rows per thread) ----
    {
        const int rh = t >> 7;              // row group 0..3 (16 rows)
        const int cg = t & 127;             // col group: cols cg*4..+3
        float a0 = 0.f, a1 = 0.f, a2 = 0.f, a3 = 0.f;
        #pragma unroll 4
        for (int s2 = 0; s2 < 16; ++s2) {
            int r = rh * 16 + s2;
            float pw = sp[r];
            us4 u = *(const us4*)((const char*)ctxs +
                        ((r * 1024 + cg * 8) ^ ((r & 7) << 4)));
            a0 += pw * bf2f(u[0]);
            a1 += pw * bf2f(u[1]);
            a2 += pw * bf2f(u[2]);
            a3 += pw * bf2f(u[3]);
        }
        float4 o = {a0, a1, a2, a3};
        *(float4*)&pvpart[rh][cg * 4] = o;
    }
    __syncthreads();
    pv_ws[(size_t)blockIdx.x * 512 + t] =
        pvpart[0][t] + pvpart[1][t] + pvpart[2][t] + pvpart[3][t];
}

// ---- fused tail: exact softmax merge + attn + ctxv + output GEMM ----
__global__ __launch_bounds__(256) void tail_kernel(
    const float* __restrict__ pv, const float* __restrict__ ml,
    const float* __restrict__ scores, const float* __restrict__ input,
    const float* __restrict__ W_out, const float* __restrict__ b_out,
    float* __restrict__ x, float* __restrict__ attn)
{
    int b = blockIdx.x, hf = blockIdx.y, t = threadIdx.x;
    __shared__ float sw[32];
    __shared__ float scm[1024];
    __shared__ float mlds[2];
    if (t < 32) {
        float m = ml[(b * 32 + t) * 2];
        float l = ml[(b * 32 + t) * 2 + 1];
        float mx = m;
        #pragma unroll
        for (int mm = 16; mm >= 1; mm >>= 1) mx = fmaxf(mx, __shfl_xor(mx, mm, 64));
        float wgt = __expf(m - mx);
        sw[t] = wgt;
        float ls = wgt * l;
        #pragma unroll
        for (int mm = 16; mm >= 1; mm >>= 1) ls += __shfl_xor(ls, mm, 64);
        if (t == 0) { mlds[0] = mx; mlds[1] = 1.f / ls; }
    }
    __syncthreads();
    const float mstar = mlds[0], invL = mlds[1];

    {   // ctxv -> scm[0..511]
        int d0 = t * 2;
        float c0 = 0.f, c1 = 0.f;
        #pragma unroll 4
        for (int j = 0; j < 32; ++j) {
            float wgt = sw[j];
            const float2 v = *(const float2*)(pv + (size_t)(b * 32 + j) * 512 + d0);
            c0 += wgt * v.x; c1 += wgt * v.y;
        }
        scm[d0] = c0 * invL; scm[d0 + 1] = c1 * invL;
    }
    for (int i = t; i < DI; i += 256) scm[512 + i] = input[b * DI + i];
    if (hf == 0) {
        #pragma unroll
        for (int k = 0; k < 8; ++k) {
            int s = k * 256 + t;
            attn[(size_t)b * S_ + s] = __expf(scores[(size_t)b * S_ + s] - mstar) * invL;
        }
    }
    __syncthreads();

    int e = hf * 256 + t;
    float a = b_out[e];
    #pragma unroll 4
    for (int d = 0; d < 1024; ++d) a += scm[d] * W_out[(size_t)d * DI + e];
    x[b * DI + e] = fast_tanh(a);
}

extern "C" void kernel_launch(void* const* d_in, const int* in_sizes, int n_in,
                              void* d_out, int out_size, void* d_ws, size_t ws_size,
                              hipStream_t stream) {
    const float* input = (const float*)d_in[0];
    const float* ctx   = (const float*)d_in[1];
    const int*   mask  = (const int*)d_in[2];
    const float* W_in  = (const float*)d_in[3];
    const float* b_in  = (const float*)d_in[4];
    const float* W_ctx = (const float*)d_in[5];
    const float* b_ctx = (const float*)d_in[6];
    const float* wsc   = (const float*)d_in[7];
    const float* W_out = (const float*)d_in[8];
    const float* b_out = (const float*)d_in[9];

    float* x_out = (float*)d_out;               // [B, DI]
    float* attn  = (float*)d_out + B_ * DI;     // [B, S]

    const int NTILE = (B_ * S_) / 64;           // 4096 tiles of 64 rows

    char* ws = (char*)d_ws;
    float* qb = (float*)ws;                    ws += (size_t)B_ * DC * 4;
    unsigned short* WtF = (unsigned short*)ws; ws += (size_t)DC * DC * 2;
    float* scores_ws = (float*)ws;             ws += (size_t)B_ * S_ * 4;
    float* pv_ws = (float*)ws;                 ws += (size_t)NTILE * 512 * 4;
    float* ml_ws = (float*)ws;                 ws += (size_t)NTILE * 2 * 4;

    prep_kernel<<<640, 256, 0, stream>>>(input, W_in, b_in, b_ctx, W_ctx, qb, WtF);
    score_kernel<<<NTILE, 512, 0, stream>>>(ctx, WtF, qb, wsc, mask,
                                            scores_ws, pv_ws, ml_ws);
    tail_kernel<<<dim3(B_, 2), 256, 0, stream>>>(pv_ws, ml_ws, scores_ws, input,
                                                 W_out, b_out, x_out, attn);
}